// Round 4
// baseline (751.401 us; speedup 1.0000x reference)
//
#include <hip/hip_runtime.h>
#include <cmath>

// Problem constants
#define Bn 4
#define Sn 2048
#define En 256
#define Hn 8
#define Dn 32
#define KD 256          // inner GEMM dim (= En)

static constexpr float SCALE_F = 0.17677669529663687f;  // 32^-0.5

// ---------- lengths[b] = sum(mask[b,:]) ----------
__global__ __launch_bounds__(256) void len_kernel(const int* __restrict__ mask,
                                                  int* __restrict__ len) {
  int b = blockIdx.x, t = threadIdx.x;
  int s = 0;
  for (int i = t; i < Sn; i += 256) s += mask[b * Sn + i];
#pragma unroll
  for (int off = 32; off > 0; off >>= 1) s += __shfl_down(s, off, 64);
  __shared__ int red[4];
  if ((t & 63) == 0) red[t >> 6] = s;
  __syncthreads();
  if (t == 0) len[b] = red[0] + red[1] + red[2] + red[3];
}

// ---------- tiled GEMM: C[M,N] = A[M,256] @ W[N,256]^T  (all fp32) ----------
// EPI==0: A = x, W0/1/2 = Wq/Wk/Wv, N=768; writes fp32 Q*SCALE,K,V in (B,H,S,D) layout
// EPI==1: A = P (fp32 scrambled), W0 = Wo, N=256; writes fp32 d_out
template <int BM, int BN, int TM, int TN, int EPI>
__global__ __launch_bounds__(256) void gemm_k(
    const float* __restrict__ Ap,
    const float* __restrict__ W0,
    const float* __restrict__ W1,
    const float* __restrict__ W2,
    float* __restrict__ O0, float* __restrict__ O1, float* __restrict__ O2,
    float* __restrict__ Oout) {
  constexpr int BK = 32;
  __shared__ __align__(16) float As[BK][BM + 4];  // k-major (transposed) tiles
  __shared__ __align__(16) float Bs[BK][BN + 4];
  const int tid = threadIdx.x;
  const int j0 = blockIdx.x * BN;
  const int i0 = blockIdx.y * BM;

  const float* Wp;
  int jc0;
  if constexpr (EPI == 0) {
    const int mat = j0 >> 8;                       // 0=Q 1=K 2=V (BN=128 never crosses)
    Wp = (mat == 0) ? W0 : ((mat == 1) ? W1 : W2);
    jc0 = j0 & 255;
  } else {
    Wp = W0;
    jc0 = j0;
  }

  float acc[TM][TN];
#pragma unroll
  for (int ii = 0; ii < TM; ++ii)
#pragma unroll
    for (int jj = 0; jj < TN; ++jj) acc[ii][jj] = 0.f;

  for (int k0 = 0; k0 < KD; k0 += BK) {
    // ---- stage A tile [BM x BK] -> As[k][m]
#pragma unroll
    for (int it = 0; it < (BM * BK / 4) / 256; ++it) {
      int c4 = tid + it * 256;
      int row = c4 >> 3, kk4 = (c4 & 7) * 4;      // 8 chunks of 4 per 32-wide row
      float4 v = *(const float4*)&Ap[(size_t)(i0 + row) * KD + k0 + kk4];
      As[kk4 + 0][row] = v.x; As[kk4 + 1][row] = v.y;
      As[kk4 + 2][row] = v.z; As[kk4 + 3][row] = v.w;
    }
    // ---- stage B tile [BN x BK] -> Bs[k][n]
#pragma unroll
    for (int it = 0; it < (BN * BK / 4) / 256; ++it) {
      int c4 = tid + it * 256;
      int row = c4 >> 3, kk4 = (c4 & 7) * 4;
      float4 v = *(const float4*)&Wp[(size_t)(jc0 + row) * KD + k0 + kk4];
      Bs[kk4 + 0][row] = v.x; Bs[kk4 + 1][row] = v.y;
      Bs[kk4 + 2][row] = v.z; Bs[kk4 + 3][row] = v.w;
    }
    __syncthreads();
    {
      const int tx = tid & 15, ty = tid >> 4;  // BN/TN == BM/TM == 16 for both configs
#pragma unroll
      for (int kk = 0; kk < BK; ++kk) {
        float a[TM], bb[TN];
#pragma unroll
        for (int ii = 0; ii < TM; ++ii) a[ii] = As[kk][ty * TM + ii];
#pragma unroll
        for (int jj = 0; jj < TN; ++jj) bb[jj] = Bs[kk][tx * TN + jj];
#pragma unroll
        for (int ii = 0; ii < TM; ++ii)
#pragma unroll
          for (int jj = 0; jj < TN; ++jj)
            acc[ii][jj] = fmaf(a[ii], bb[jj], acc[ii][jj]);
      }
    }
    __syncthreads();
  }

  const int tx = tid & 15, ty = tid >> 4;
  if constexpr (EPI == 0) {
    const int mat = j0 >> 8;
    float* obase = (mat == 0) ? O0 : ((mat == 1) ? O1 : O2);
    const float scale = (mat == 0) ? SCALE_F : 1.0f;  // fold softmax scale into Q
#pragma unroll
    for (int ii = 0; ii < TM; ++ii) {
      int i = i0 + ty * TM + ii;
      int bb_ = i >> 11, s = i & (Sn - 1);
#pragma unroll
      for (int jj = 0; jj < TN; jj += 4) {
        int c = jc0 + tx * TN + jj;  // 0..255, 4-aligned -> same head
        int h = c >> 5, d = c & 31;
        float4 v = make_float4(acc[ii][jj] * scale, acc[ii][jj + 1] * scale,
                               acc[ii][jj + 2] * scale, acc[ii][jj + 3] * scale);
        *(float4*)&obase[((size_t)(bb_ * Hn + h) * Sn + s) * Dn + d] = v;
      }
    }
  } else {
#pragma unroll
    for (int ii = 0; ii < TM; ++ii) {
      int i = i0 + ty * TM + ii;
#pragma unroll
      for (int jj = 0; jj < TN; jj += 4) {
        int j = j0 + tx * TN + jj;
        float4 v = make_float4(acc[ii][jj], acc[ii][jj + 1],
                               acc[ii][jj + 2], acc[ii][jj + 3]);
        *(float4*)&Oout[(size_t)i * En + j] = v;   // fp32 output (reference dtype)
      }
    }
  }
}

// ---------- flash attention, thread-per-query, full key range, direct P write ----------
// Writes normalized output straight into scrambled layout: P[b].flat[h*L*D + q*D + d]
__global__ __launch_bounds__(128) void attn_kernel(
    const float* __restrict__ Qg, const float* __restrict__ Kg,
    const float* __restrict__ Vg, const int* __restrict__ len,
    float* __restrict__ P) {
  const int qblk = blockIdx.x;
  const int h = blockIdx.y, b = blockIdx.z;
  const int L = len[b];
  const int q0 = qblk * 128;
  if (q0 >= L) return;  // queries >= L never reach the output (block-uniform exit)

  const int t = threadIdx.x;
  const int q = q0 + t;
  const bool active = q < L;
  const size_t bh = (size_t)(b * Hn + h) * Sn;

  float qr[32];
  if (active) {
    const float4* qp = (const float4*)&Qg[(bh + q) * Dn];
#pragma unroll
    for (int i = 0; i < 8; ++i) {
      float4 v = qp[i];
      qr[i * 4 + 0] = v.x; qr[i * 4 + 1] = v.y;
      qr[i * 4 + 2] = v.z; qr[i * 4 + 3] = v.w;
    }
  } else {
#pragma unroll
    for (int d = 0; d < 32; ++d) qr[d] = 0.f;
  }

  __shared__ __align__(16) float Kld[64][36];  // stride 36: aligned rows, broken bank stride
  __shared__ __align__(16) float Vld[64][36];

  float m = -INFINITY, l = 0.f;
  float acc[32];
#pragma unroll
  for (int d = 0; d < 32; ++d) acc[d] = 0.f;

  for (int k0 = 0; k0 < L; k0 += 64) {
    const int nk = min(64, L - k0);
    __syncthreads();
#pragma unroll
    for (int it = 0; it < 4; ++it) {  // 128 thr load 64x32 K and V tiles, coalesced
      int f4 = t + it * 128;
      int row = f4 >> 3, c4 = (f4 & 7) * 4;
      if (row < nk) {
        *(float4*)&Kld[row][c4] = *(const float4*)&Kg[(bh + k0 + row) * Dn + c4];
        *(float4*)&Vld[row][c4] = *(const float4*)&Vg[(bh + k0 + row) * Dn + c4];
      }
    }
    __syncthreads();
    for (int kk = 0; kk < nk; ++kk) {
      const float4* kp = (const float4*)&Kld[kk][0];  // LDS broadcast reads
      float s0 = 0.f, s1 = 0.f, s2 = 0.f, s3 = 0.f;
#pragma unroll
      for (int i = 0; i < 8; ++i) {
        float4 kv = kp[i];
        s0 = fmaf(qr[i * 4 + 0], kv.x, s0);
        s1 = fmaf(qr[i * 4 + 1], kv.y, s1);
        s2 = fmaf(qr[i * 4 + 2], kv.z, s2);
        s3 = fmaf(qr[i * 4 + 3], kv.w, s3);
      }
      float s = (s0 + s1) + (s2 + s3);       // SCALE already folded into Q
      float nm = fmaxf(m, s);
      float p = __expf(s - nm);
      float sc = __expf(m - nm);
      l = l * sc + p;
      const float4* vp = (const float4*)&Vld[kk][0];
#pragma unroll
      for (int i = 0; i < 8; ++i) {
        float4 vv = vp[i];
        acc[i * 4 + 0] = fmaf(acc[i * 4 + 0], sc, p * vv.x);
        acc[i * 4 + 1] = fmaf(acc[i * 4 + 1], sc, p * vv.y);
        acc[i * 4 + 2] = fmaf(acc[i * 4 + 2], sc, p * vv.z);
        acc[i * 4 + 3] = fmaf(acc[i * 4 + 3], sc, p * vv.w);
      }
      m = nm;
    }
  }
  if (active) {
    const float inv = 1.0f / l;  // l >= 1 (max key contributes exp(0)=1)
    float* dst = &P[(size_t)b * Sn * En + (size_t)h * L * Dn + (size_t)q * Dn];
#pragma unroll
    for (int i = 0; i < 8; ++i) {
      float4 v = make_float4(acc[i * 4] * inv, acc[i * 4 + 1] * inv,
                             acc[i * 4 + 2] * inv, acc[i * 4 + 3] * inv);
      *(float4*)&dst[i * 4] = v;
    }
  }
}

// ---------- zero P tail [L*E, S*E) per batch ----------
__global__ __launch_bounds__(256) void ztail_kernel(const int* __restrict__ len,
                                                    float* __restrict__ P) {
  const int b = blockIdx.y;
  const int L = len[b];
  const int idx = (blockIdx.x * 256 + threadIdx.x) * 4;
  if (idx >= L * En)
    *(float4*)&P[(size_t)b * Sn * En + idx] = make_float4(0.f, 0.f, 0.f, 0.f);
}

extern "C" void kernel_launch(void* const* d_in, const int* in_sizes, int n_in,
                              void* d_out, int out_size, void* d_ws, size_t ws_size,
                              hipStream_t stream) {
  (void)in_sizes; (void)n_in; (void)out_size; (void)ws_size;
  const float* x  = (const float*)d_in[0];  // fp32 (B,S,E) — proven by R2/R3 forensics
  const int* mask = (const int*)d_in[1];    // int32 (B,S)
  const float* Wq = (const float*)d_in[2];  // fp32 (E,E)
  const float* Wk = (const float*)d_in[3];
  const float* Wv = (const float*)d_in[4];
  const float* Wo = (const float*)d_in[5];
  float* out = (float*)d_out;               // fp32 (B,S,E) — reference output dtype

  // workspace layout (fp32): lengths[4] (+pad) | Q | K | V | P   (~33.6 MB)
  float* wsf = (float*)d_ws;
  int* lengths = (int*)d_ws;
  const size_t BHSD = (size_t)Bn * Hn * Sn * Dn;  // 2,097,152
  float* Qw = wsf + 64;
  float* Kw = Qw + BHSD;
  float* Vw = Kw + BHSD;
  float* Pw = Vw + BHSD;

  len_kernel<<<dim3(Bn), 256, 0, stream>>>(mask, lengths);
  gemm_k<128, 128, 8, 8, 0><<<dim3(6, 64), 256, 0, stream>>>(
      x, Wq, Wk, Wv, Qw, Kw, Vw, nullptr);
  attn_kernel<<<dim3(Sn / 128, Hn, Bn), 128, 0, stream>>>(Qw, Kw, Vw, lengths, Pw);
  ztail_kernel<<<dim3(Sn * En / 1024, Bn), 256, 0, stream>>>(lengths, Pw);
  gemm_k<64, 128, 4, 8, 1><<<dim3(2, 128), 256, 0, stream>>>(
      Pw, Wo, Wo, Wo, nullptr, nullptr, nullptr, out);
}

// Round 5
// 428.784 us; speedup vs baseline: 1.7524x; 1.7524x over previous
//
#include <hip/hip_runtime.h>
#include <cmath>

// Problem constants
#define Bn 4
#define Sn 2048
#define En 256
#define Hn 8
#define Dn 32
#define KD 256          // inner GEMM dim (= En)
#define NSPLIT 4        // key-split factor for attention

static constexpr float SCALE_F = 0.17677669529663687f;  // 32^-0.5

// ---------- lengths[b] = sum(mask[b,:]) ----------
__global__ __launch_bounds__(256) void len_kernel(const int* __restrict__ mask,
                                                  int* __restrict__ len) {
  int b = blockIdx.x, t = threadIdx.x;
  int s = 0;
  for (int i = t; i < Sn; i += 256) s += mask[b * Sn + i];
#pragma unroll
  for (int off = 32; off > 0; off >>= 1) s += __shfl_down(s, off, 64);
  __shared__ int red[4];
  if ((t & 63) == 0) red[t >> 6] = s;
  __syncthreads();
  if (t == 0) len[b] = red[0] + red[1] + red[2] + red[3];
}

// ---------- tiled GEMM: C[M,N] = A[M,256] @ W[N,256]^T  (all fp32) ----------
// EPI==0: A = x, W0/1/2 = Wq/Wk/Wv, N=768; writes fp32 Q*SCALE,K,V in (B,H,S,D) layout
// EPI==1: A = P (fp32 scrambled), W0 = Wo, N=256; writes fp32 d_out
template <int BM, int BN, int TM, int TN, int EPI>
__global__ __launch_bounds__(256) void gemm_k(
    const float* __restrict__ Ap,
    const float* __restrict__ W0,
    const float* __restrict__ W1,
    const float* __restrict__ W2,
    float* __restrict__ O0, float* __restrict__ O1, float* __restrict__ O2,
    float* __restrict__ Oout) {
  constexpr int BK = 32;
  __shared__ __align__(16) float As[BK][BM + 4];  // k-major (transposed) tiles
  __shared__ __align__(16) float Bs[BK][BN + 4];
  const int tid = threadIdx.x;
  const int j0 = blockIdx.x * BN;
  const int i0 = blockIdx.y * BM;

  const float* Wp;
  int jc0;
  if constexpr (EPI == 0) {
    const int mat = j0 >> 8;                       // 0=Q 1=K 2=V (BN=128 never crosses)
    Wp = (mat == 0) ? W0 : ((mat == 1) ? W1 : W2);
    jc0 = j0 & 255;
  } else {
    Wp = W0;
    jc0 = j0;
  }

  float acc[TM][TN];
#pragma unroll
  for (int ii = 0; ii < TM; ++ii)
#pragma unroll
    for (int jj = 0; jj < TN; ++jj) acc[ii][jj] = 0.f;

  for (int k0 = 0; k0 < KD; k0 += BK) {
#pragma unroll
    for (int it = 0; it < (BM * BK / 4) / 256; ++it) {
      int c4 = tid + it * 256;
      int row = c4 >> 3, kk4 = (c4 & 7) * 4;
      float4 v = *(const float4*)&Ap[(size_t)(i0 + row) * KD + k0 + kk4];
      As[kk4 + 0][row] = v.x; As[kk4 + 1][row] = v.y;
      As[kk4 + 2][row] = v.z; As[kk4 + 3][row] = v.w;
    }
#pragma unroll
    for (int it = 0; it < (BN * BK / 4) / 256; ++it) {
      int c4 = tid + it * 256;
      int row = c4 >> 3, kk4 = (c4 & 7) * 4;
      float4 v = *(const float4*)&Wp[(size_t)(jc0 + row) * KD + k0 + kk4];
      Bs[kk4 + 0][row] = v.x; Bs[kk4 + 1][row] = v.y;
      Bs[kk4 + 2][row] = v.z; Bs[kk4 + 3][row] = v.w;
    }
    __syncthreads();
    {
      const int tx = tid & 15, ty = tid >> 4;
#pragma unroll
      for (int kk = 0; kk < BK; ++kk) {
        float a[TM], bb[TN];
#pragma unroll
        for (int ii = 0; ii < TM; ++ii) a[ii] = As[kk][ty * TM + ii];
#pragma unroll
        for (int jj = 0; jj < TN; ++jj) bb[jj] = Bs[kk][tx * TN + jj];
#pragma unroll
        for (int ii = 0; ii < TM; ++ii)
#pragma unroll
          for (int jj = 0; jj < TN; ++jj)
            acc[ii][jj] = fmaf(a[ii], bb[jj], acc[ii][jj]);
      }
    }
    __syncthreads();
  }

  const int tx = tid & 15, ty = tid >> 4;
  if constexpr (EPI == 0) {
    const int mat = j0 >> 8;
    float* obase = (mat == 0) ? O0 : ((mat == 1) ? O1 : O2);
    const float scale = (mat == 0) ? SCALE_F : 1.0f;  // fold softmax scale into Q
#pragma unroll
    for (int ii = 0; ii < TM; ++ii) {
      int i = i0 + ty * TM + ii;
      int bb_ = i >> 11, s = i & (Sn - 1);
#pragma unroll
      for (int jj = 0; jj < TN; jj += 4) {
        int c = jc0 + tx * TN + jj;  // 4-aligned -> same head
        int h = c >> 5, d = c & 31;
        float4 v = make_float4(acc[ii][jj] * scale, acc[ii][jj + 1] * scale,
                               acc[ii][jj + 2] * scale, acc[ii][jj + 3] * scale);
        *(float4*)&obase[((size_t)(bb_ * Hn + h) * Sn + s) * Dn + d] = v;
      }
    }
  } else {
#pragma unroll
    for (int ii = 0; ii < TM; ++ii) {
      int i = i0 + ty * TM + ii;
#pragma unroll
      for (int jj = 0; jj < TN; jj += 4) {
        int j = j0 + tx * TN + jj;
        float4 v = make_float4(acc[ii][jj], acc[ii][jj + 1],
                               acc[ii][jj + 2], acc[ii][jj + 3]);
        *(float4*)&Oout[(size_t)i * En + j] = v;
      }
    }
  }
}

// ---------- flash attention, thread-per-query, key-split x NSPLIT, 8-key groups ----
// part[((b*H+h)*NSPLIT+split)*Sn + q][36]: acc[32] (unnormalized), m, l
__global__ __launch_bounds__(128) void attn_kernel(
    const float* __restrict__ Qg, const float* __restrict__ Kg,
    const float* __restrict__ Vg, const int* __restrict__ len,
    float* __restrict__ part) {
  const int split = blockIdx.x & (NSPLIT - 1);
  const int qblk = blockIdx.x >> 2;   // log2(NSPLIT)
  const int h = blockIdx.y, b = blockIdx.z;
  const int L = len[b];
  const int q0 = qblk * 128;
  if (q0 >= L) return;                 // block-uniform exit
  const int chunk = ((L + NSPLIT * 64 - 1) / (NSPLIT * 64)) * 64;
  const int ks = split * chunk;
  if (ks >= L) return;
  const int ke = min(L, ks + chunk);

  const int t = threadIdx.x;
  const int q = q0 + t;
  const bool active = q < L;
  const size_t bh = (size_t)(b * Hn + h) * Sn;

  float qr[32];
  if (active) {
    const float4* qp = (const float4*)&Qg[(bh + q) * Dn];
#pragma unroll
    for (int i = 0; i < 8; ++i) {
      float4 v = qp[i];
      qr[i * 4 + 0] = v.x; qr[i * 4 + 1] = v.y;
      qr[i * 4 + 2] = v.z; qr[i * 4 + 3] = v.w;
    }
  } else {
#pragma unroll
    for (int d = 0; d < 32; ++d) qr[d] = 0.f;
  }

  __shared__ __align__(16) float Kld[64][36];
  __shared__ __align__(16) float Vld[64][36];

  float m = -INFINITY, l = 0.f;
  float acc[32];
#pragma unroll
  for (int d = 0; d < 32; ++d) acc[d] = 0.f;

  for (int k0 = ks; k0 < ke; k0 += 64) {
    const int nk = min(64, ke - k0);
    __syncthreads();
#pragma unroll
    for (int it = 0; it < 4; ++it) {
      int f4 = t + it * 128;
      int row = f4 >> 3, c4 = (f4 & 7) * 4;
      if (row < nk) {
        *(float4*)&Kld[row][c4] = *(const float4*)&Kg[(bh + k0 + row) * Dn + c4];
        *(float4*)&Vld[row][c4] = *(const float4*)&Vg[(bh + k0 + row) * Dn + c4];
      }
    }
    __syncthreads();

    int kk = 0;
    // ---- groups of 8 keys: 8 independent score chains, 1 rescale per group ----
    for (; kk + 8 <= nk; kk += 8) {
      float s[8];
#pragma unroll
      for (int j = 0; j < 8; ++j) s[j] = 0.f;
#pragma unroll
      for (int i = 0; i < 8; ++i) {      // dim chunk (float4)
        const float qx = qr[i * 4 + 0], qy = qr[i * 4 + 1];
        const float qz = qr[i * 4 + 2], qw = qr[i * 4 + 3];
#pragma unroll
        for (int j = 0; j < 8; ++j) {
          float4 kv = *(const float4*)&Kld[kk + j][i * 4];
          s[j] = fmaf(qx, kv.x, s[j]);
          s[j] = fmaf(qy, kv.y, s[j]);
          s[j] = fmaf(qz, kv.z, s[j]);
          s[j] = fmaf(qw, kv.w, s[j]);
        }
      }
      // max tree
      float m01 = fmaxf(s[0], s[1]), m23 = fmaxf(s[2], s[3]);
      float m45 = fmaxf(s[4], s[5]), m67 = fmaxf(s[6], s[7]);
      float m8 = fmaxf(fmaxf(m01, m23), fmaxf(m45, m67));
      float nm = fmaxf(m, m8);
      float p[8];
#pragma unroll
      for (int j = 0; j < 8; ++j) p[j] = __expf(s[j] - nm);
      float sc = __expf(m - nm);
      float psum = ((p[0] + p[1]) + (p[2] + p[3])) + ((p[4] + p[5]) + (p[6] + p[7]));
      l = l * sc + psum;
      m = nm;
#pragma unroll
      for (int i = 0; i < 8; ++i) {      // dim chunk
        float ax = acc[i * 4 + 0] * sc, ay = acc[i * 4 + 1] * sc;
        float az = acc[i * 4 + 2] * sc, aw = acc[i * 4 + 3] * sc;
#pragma unroll
        for (int j = 0; j < 8; ++j) {
          float4 vv = *(const float4*)&Vld[kk + j][i * 4];
          ax = fmaf(p[j], vv.x, ax);
          ay = fmaf(p[j], vv.y, ay);
          az = fmaf(p[j], vv.z, az);
          aw = fmaf(p[j], vv.w, aw);
        }
        acc[i * 4 + 0] = ax; acc[i * 4 + 1] = ay;
        acc[i * 4 + 2] = az; acc[i * 4 + 3] = aw;
      }
    }
    // ---- remainder keys (last tile only) ----
    for (; kk < nk; ++kk) {
      const float4* kp = (const float4*)&Kld[kk][0];
      float s0 = 0.f, s1 = 0.f, s2 = 0.f, s3 = 0.f;
#pragma unroll
      for (int i = 0; i < 8; ++i) {
        float4 kv = kp[i];
        s0 = fmaf(qr[i * 4 + 0], kv.x, s0);
        s1 = fmaf(qr[i * 4 + 1], kv.y, s1);
        s2 = fmaf(qr[i * 4 + 2], kv.z, s2);
        s3 = fmaf(qr[i * 4 + 3], kv.w, s3);
      }
      float s = (s0 + s1) + (s2 + s3);
      float nm = fmaxf(m, s);
      float p = __expf(s - nm);
      float sc = __expf(m - nm);
      l = l * sc + p;
      const float4* vp = (const float4*)&Vld[kk][0];
#pragma unroll
      for (int i = 0; i < 8; ++i) {
        float4 vv = vp[i];
        acc[i * 4 + 0] = fmaf(acc[i * 4 + 0], sc, p * vv.x);
        acc[i * 4 + 1] = fmaf(acc[i * 4 + 1], sc, p * vv.y);
        acc[i * 4 + 2] = fmaf(acc[i * 4 + 2], sc, p * vv.z);
        acc[i * 4 + 3] = fmaf(acc[i * 4 + 3], sc, p * vv.w);
      }
      m = nm;
    }
  }
  if (active) {
    float* pp = &part[(((size_t)(b * Hn + h) * NSPLIT + split) * Sn + q) * 36];
#pragma unroll
    for (int i = 0; i < 8; ++i) {
      float4 v = make_float4(acc[i * 4], acc[i * 4 + 1], acc[i * 4 + 2], acc[i * 4 + 3]);
      *(float4*)&pp[i * 4] = v;
    }
    pp[32] = m;
    pp[33] = l;
  }
}

// ---------- merge key-splits, write scrambled P: P[b].flat[h*L*D + q*D + d] ----------
__global__ __launch_bounds__(256) void combine_kernel(const float* __restrict__ part,
                                                      const int* __restrict__ len,
                                                      float* __restrict__ P) {
  const int h = blockIdx.y, b = blockIdx.z;
  const int L = len[b];
  const int q = blockIdx.x * 256 + threadIdx.x;
  if (q >= L) return;
  const int chunk = ((L + NSPLIT * 64 - 1) / (NSPLIT * 64)) * 64;
  const size_t base = (size_t)(b * Hn + h) * NSPLIT * Sn;

  float M = -INFINITY;
  int ns = 0;
  float ms[NSPLIT], ls[NSPLIT];
#pragma unroll
  for (int sp = 0; sp < NSPLIT; ++sp) {
    if (sp * chunk < L) {
      const float* pp = &part[(base + (size_t)sp * Sn + q) * 36];
      ms[sp] = pp[32]; ls[sp] = pp[33];
      M = fmaxf(M, ms[sp]);
      ns = sp + 1;
    }
  }
  float T = 0.f;
  float o[32];
#pragma unroll
  for (int d = 0; d < 32; ++d) o[d] = 0.f;
  for (int sp = 0; sp < ns; ++sp) {
    float w = __expf(ms[sp] - M);
    T += ls[sp] * w;
    const float4* pp = (const float4*)&part[(base + (size_t)sp * Sn + q) * 36];
#pragma unroll
    for (int i = 0; i < 8; ++i) {
      float4 v = pp[i];
      o[i * 4 + 0] = fmaf(w, v.x, o[i * 4 + 0]);
      o[i * 4 + 1] = fmaf(w, v.y, o[i * 4 + 1]);
      o[i * 4 + 2] = fmaf(w, v.z, o[i * 4 + 2]);
      o[i * 4 + 3] = fmaf(w, v.w, o[i * 4 + 3]);
    }
  }
  const float inv = 1.0f / T;
  float* dst = &P[(size_t)b * Sn * En + (size_t)h * L * Dn + (size_t)q * Dn];
#pragma unroll
  for (int i = 0; i < 8; ++i) {
    float4 v = make_float4(o[i * 4] * inv, o[i * 4 + 1] * inv,
                           o[i * 4 + 2] * inv, o[i * 4 + 3] * inv);
    *(float4*)&dst[i * 4] = v;
  }
}

// ---------- zero P tail [L*E, S*E) per batch ----------
__global__ __launch_bounds__(256) void ztail_kernel(const int* __restrict__ len,
                                                    float* __restrict__ P) {
  const int b = blockIdx.y;
  const int L = len[b];
  const int idx = (blockIdx.x * 256 + threadIdx.x) * 4;
  if (idx >= L * En)
    *(float4*)&P[(size_t)b * Sn * En + idx] = make_float4(0.f, 0.f, 0.f, 0.f);
}

extern "C" void kernel_launch(void* const* d_in, const int* in_sizes, int n_in,
                              void* d_out, int out_size, void* d_ws, size_t ws_size,
                              hipStream_t stream) {
  (void)in_sizes; (void)n_in; (void)out_size; (void)ws_size;
  const float* x  = (const float*)d_in[0];  // fp32 (B,S,E)
  const int* mask = (const int*)d_in[1];    // int32 (B,S)
  const float* Wq = (const float*)d_in[2];  // fp32 (E,E)
  const float* Wk = (const float*)d_in[3];
  const float* Wv = (const float*)d_in[4];
  const float* Wo = (const float*)d_in[5];
  float* out = (float*)d_out;               // fp32 (B,S,E)

  // workspace (fp32): lengths | Q | K | V | P | partials  (~71 MB, proven safe in R1)
  float* wsf = (float*)d_ws;
  int* lengths = (int*)d_ws;
  const size_t BHSD = (size_t)Bn * Hn * Sn * Dn;  // 2,097,152
  float* Qw = wsf + 64;
  float* Kw = Qw + BHSD;
  float* Vw = Kw + BHSD;
  float* Pw = Vw + BHSD;
  float* part = Pw + (size_t)Bn * Sn * En;

  len_kernel<<<dim3(Bn), 256, 0, stream>>>(mask, lengths);
  gemm_k<128, 128, 8, 8, 0><<<dim3(6, 64), 256, 0, stream>>>(
      x, Wq, Wk, Wv, Qw, Kw, Vw, nullptr);
  attn_kernel<<<dim3((Sn / 128) * NSPLIT, Hn, Bn), 128, 0, stream>>>(
      Qw, Kw, Vw, lengths, part);
  combine_kernel<<<dim3(Sn / 256, Hn, Bn), 256, 0, stream>>>(part, lengths, Pw);
  ztail_kernel<<<dim3(Sn * En / 1024, Bn), 256, 0, stream>>>(lengths, Pw);
  gemm_k<64, 128, 4, 8, 1><<<dim3(2, 128), 256, 0, stream>>>(
      Pw, Wo, Wo, Wo, nullptr, nullptr, nullptr, out);
}

// Round 6
// 386.341 us; speedup vs baseline: 1.9449x; 1.1099x over previous
//
#include <hip/hip_runtime.h>
#include <cmath>

// Problem constants
#define Bn 4
#define Sn 2048
#define En 256
#define Hn 8
#define Dn 32
#define KD 256          // inner GEMM dim (= En)

static constexpr float SCALE_F = 0.17677669529663687f;  // 32^-0.5

// ---------- lengths[b] = sum(mask[b,:]) ----------
__global__ __launch_bounds__(256) void len_kernel(const int* __restrict__ mask,
                                                  int* __restrict__ len) {
  int b = blockIdx.x, t = threadIdx.x;
  int s = 0;
  for (int i = t; i < Sn; i += 256) s += mask[b * Sn + i];
#pragma unroll
  for (int off = 32; off > 0; off >>= 1) s += __shfl_down(s, off, 64);
  __shared__ int red[4];
  if ((t & 63) == 0) red[t >> 6] = s;
  __syncthreads();
  if (t == 0) len[b] = red[0] + red[1] + red[2] + red[3];
}

// ---------- tiled GEMM: C[M,N] = A[M,256] @ W[N,256]^T  (all fp32) ----------
// EPI==0: A = x, W0/1/2 = Wq/Wk/Wv, N=768; writes fp32 Q*SCALE,K,V in (B,H,S,D) layout
// EPI==1: A = P (fp32 scrambled), W0 = Wo, N=256; writes fp32 d_out
template <int BM, int BN, int TM, int TN, int EPI>
__global__ __launch_bounds__(256) void gemm_k(
    const float* __restrict__ Ap,
    const float* __restrict__ W0,
    const float* __restrict__ W1,
    const float* __restrict__ W2,
    float* __restrict__ O0, float* __restrict__ O1, float* __restrict__ O2,
    float* __restrict__ Oout) {
  constexpr int BK = 32;
  __shared__ __align__(16) float As[BK][BM + 4];  // k-major (transposed) tiles
  __shared__ __align__(16) float Bs[BK][BN + 4];
  const int tid = threadIdx.x;
  const int j0 = blockIdx.x * BN;
  const int i0 = blockIdx.y * BM;

  const float* Wp;
  int jc0;
  if constexpr (EPI == 0) {
    const int mat = j0 >> 8;                       // 0=Q 1=K 2=V (BN=128 never crosses)
    Wp = (mat == 0) ? W0 : ((mat == 1) ? W1 : W2);
    jc0 = j0 & 255;
  } else {
    Wp = W0;
    jc0 = j0;
  }

  float acc[TM][TN];
#pragma unroll
  for (int ii = 0; ii < TM; ++ii)
#pragma unroll
    for (int jj = 0; jj < TN; ++jj) acc[ii][jj] = 0.f;

  for (int k0 = 0; k0 < KD; k0 += BK) {
#pragma unroll
    for (int it = 0; it < (BM * BK / 4) / 256; ++it) {
      int c4 = tid + it * 256;
      int row = c4 >> 3, kk4 = (c4 & 7) * 4;
      float4 v = *(const float4*)&Ap[(size_t)(i0 + row) * KD + k0 + kk4];
      As[kk4 + 0][row] = v.x; As[kk4 + 1][row] = v.y;
      As[kk4 + 2][row] = v.z; As[kk4 + 3][row] = v.w;
    }
#pragma unroll
    for (int it = 0; it < (BN * BK / 4) / 256; ++it) {
      int c4 = tid + it * 256;
      int row = c4 >> 3, kk4 = (c4 & 7) * 4;
      float4 v = *(const float4*)&Wp[(size_t)(jc0 + row) * KD + k0 + kk4];
      Bs[kk4 + 0][row] = v.x; Bs[kk4 + 1][row] = v.y;
      Bs[kk4 + 2][row] = v.z; Bs[kk4 + 3][row] = v.w;
    }
    __syncthreads();
    {
      const int tx = tid & 15, ty = tid >> 4;
#pragma unroll
      for (int kk = 0; kk < BK; ++kk) {
        float a[TM], bb[TN];
#pragma unroll
        for (int ii = 0; ii < TM; ++ii) a[ii] = As[kk][ty * TM + ii];
#pragma unroll
        for (int jj = 0; jj < TN; ++jj) bb[jj] = Bs[kk][tx * TN + jj];
#pragma unroll
        for (int ii = 0; ii < TM; ++ii)
#pragma unroll
          for (int jj = 0; jj < TN; ++jj)
            acc[ii][jj] = fmaf(a[ii], bb[jj], acc[ii][jj]);
      }
    }
    __syncthreads();
  }

  const int tx = tid & 15, ty = tid >> 4;
  if constexpr (EPI == 0) {
    const int mat = j0 >> 8;
    float* obase = (mat == 0) ? O0 : ((mat == 1) ? O1 : O2);
    const float scale = (mat == 0) ? SCALE_F : 1.0f;  // fold softmax scale into Q
#pragma unroll
    for (int ii = 0; ii < TM; ++ii) {
      int i = i0 + ty * TM + ii;
      int bb_ = i >> 11, s = i & (Sn - 1);
#pragma unroll
      for (int jj = 0; jj < TN; jj += 4) {
        int c = jc0 + tx * TN + jj;  // 4-aligned -> same head
        int h = c >> 5, d = c & 31;
        float4 v = make_float4(acc[ii][jj] * scale, acc[ii][jj + 1] * scale,
                               acc[ii][jj + 2] * scale, acc[ii][jj + 3] * scale);
        *(float4*)&obase[((size_t)(bb_ * Hn + h) * Sn + s) * Dn + d] = v;
      }
    }
  } else {
#pragma unroll
    for (int ii = 0; ii < TM; ++ii) {
      int i = i0 + ty * TM + ii;
#pragma unroll
      for (int jj = 0; jj < TN; jj += 4) {
        int j = j0 + tx * TN + jj;
        float4 v = make_float4(acc[ii][jj], acc[ii][jj + 1],
                               acc[ii][jj + 2], acc[ii][jj + 3]);
        *(float4*)&Oout[(size_t)i * En + j] = v;
      }
    }
  }
}

// ---------- flash attention, thread-per-query, key-split x NS, 8-key groups ----
// pacc[((b*H+h)*NS+split)*Sn + q][32] : unnormalized acc
// pml [((b*H+h)*NS+split)*Sn + q][2]  : (m, l)
template <int NS>
__global__ __launch_bounds__(128) void attn_kernel(
    const float* __restrict__ Qg, const float* __restrict__ Kg,
    const float* __restrict__ Vg, const int* __restrict__ len,
    float* __restrict__ pacc, float* __restrict__ pml) {
  constexpr int LOG = (NS == 8) ? 3 : 2;
  const int split = blockIdx.x & (NS - 1);
  const int qblk = blockIdx.x >> LOG;
  const int h = blockIdx.y, b = blockIdx.z;
  const int L = len[b];
  const int q0 = qblk * 128;
  if (q0 >= L) return;                 // block-uniform exit
  const int chunk = ((L + NS * 64 - 1) / (NS * 64)) * 64;
  const int ks = split * chunk;
  if (ks >= L) return;
  const int ke = min(L, ks + chunk);

  const int t = threadIdx.x;
  const int q = q0 + t;
  const bool active = q < L;
  const size_t bh = (size_t)(b * Hn + h) * Sn;

  float qr[32];
  if (active) {
    const float4* qp = (const float4*)&Qg[(bh + q) * Dn];
#pragma unroll
    for (int i = 0; i < 8; ++i) {
      float4 v = qp[i];
      qr[i * 4 + 0] = v.x; qr[i * 4 + 1] = v.y;
      qr[i * 4 + 2] = v.z; qr[i * 4 + 3] = v.w;
    }
  } else {
#pragma unroll
    for (int d = 0; d < 32; ++d) qr[d] = 0.f;
  }

  __shared__ __align__(16) float Kld[64][36];
  __shared__ __align__(16) float Vld[64][36];

  float m = -INFINITY, l = 0.f;
  float acc[32];
#pragma unroll
  for (int d = 0; d < 32; ++d) acc[d] = 0.f;

  for (int k0 = ks; k0 < ke; k0 += 64) {
    const int nk = min(64, ke - k0);
    __syncthreads();
#pragma unroll
    for (int it = 0; it < 4; ++it) {
      int f4 = t + it * 128;
      int row = f4 >> 3, c4 = (f4 & 7) * 4;
      if (row < nk) {
        *(float4*)&Kld[row][c4] = *(const float4*)&Kg[(bh + k0 + row) * Dn + c4];
        *(float4*)&Vld[row][c4] = *(const float4*)&Vg[(bh + k0 + row) * Dn + c4];
      }
    }
    __syncthreads();

    int kk = 0;
    // ---- groups of 8 keys: 8 independent score chains, 1 rescale per group ----
    for (; kk + 8 <= nk; kk += 8) {
      float s[8];
#pragma unroll
      for (int j = 0; j < 8; ++j) s[j] = 0.f;
#pragma unroll
      for (int i = 0; i < 8; ++i) {      // dim chunk (float4)
        const float qx = qr[i * 4 + 0], qy = qr[i * 4 + 1];
        const float qz = qr[i * 4 + 2], qw = qr[i * 4 + 3];
#pragma unroll
        for (int j = 0; j < 8; ++j) {
          float4 kv = *(const float4*)&Kld[kk + j][i * 4];
          s[j] = fmaf(qx, kv.x, s[j]);
          s[j] = fmaf(qy, kv.y, s[j]);
          s[j] = fmaf(qz, kv.z, s[j]);
          s[j] = fmaf(qw, kv.w, s[j]);
        }
      }
      float m01 = fmaxf(s[0], s[1]), m23 = fmaxf(s[2], s[3]);
      float m45 = fmaxf(s[4], s[5]), m67 = fmaxf(s[6], s[7]);
      float m8 = fmaxf(fmaxf(m01, m23), fmaxf(m45, m67));
      float nm = fmaxf(m, m8);
      float p[8];
#pragma unroll
      for (int j = 0; j < 8; ++j) p[j] = __expf(s[j] - nm);
      float sc = __expf(m - nm);
      float psum = ((p[0] + p[1]) + (p[2] + p[3])) + ((p[4] + p[5]) + (p[6] + p[7]));
      l = l * sc + psum;
      m = nm;
#pragma unroll
      for (int i = 0; i < 8; ++i) {      // dim chunk
        float ax = acc[i * 4 + 0] * sc, ay = acc[i * 4 + 1] * sc;
        float az = acc[i * 4 + 2] * sc, aw = acc[i * 4 + 3] * sc;
#pragma unroll
        for (int j = 0; j < 8; ++j) {
          float4 vv = *(const float4*)&Vld[kk + j][i * 4];
          ax = fmaf(p[j], vv.x, ax);
          ay = fmaf(p[j], vv.y, ay);
          az = fmaf(p[j], vv.z, az);
          aw = fmaf(p[j], vv.w, aw);
        }
        acc[i * 4 + 0] = ax; acc[i * 4 + 1] = ay;
        acc[i * 4 + 2] = az; acc[i * 4 + 3] = aw;
      }
    }
    // ---- remainder keys (last tile only) ----
    for (; kk < nk; ++kk) {
      const float4* kp = (const float4*)&Kld[kk][0];
      float s0 = 0.f, s1 = 0.f, s2 = 0.f, s3 = 0.f;
#pragma unroll
      for (int i = 0; i < 8; ++i) {
        float4 kv = kp[i];
        s0 = fmaf(qr[i * 4 + 0], kv.x, s0);
        s1 = fmaf(qr[i * 4 + 1], kv.y, s1);
        s2 = fmaf(qr[i * 4 + 2], kv.z, s2);
        s3 = fmaf(qr[i * 4 + 3], kv.w, s3);
      }
      float s = (s0 + s1) + (s2 + s3);
      float nm = fmaxf(m, s);
      float p = __expf(s - nm);
      float sc = __expf(m - nm);
      l = l * sc + p;
      const float4* vp = (const float4*)&Vld[kk][0];
#pragma unroll
      for (int i = 0; i < 8; ++i) {
        float4 vv = vp[i];
        acc[i * 4 + 0] = fmaf(acc[i * 4 + 0], sc, p * vv.x);
        acc[i * 4 + 1] = fmaf(acc[i * 4 + 1], sc, p * vv.y);
        acc[i * 4 + 2] = fmaf(acc[i * 4 + 2], sc, p * vv.z);
        acc[i * 4 + 3] = fmaf(acc[i * 4 + 3], sc, p * vv.w);
      }
      m = nm;
    }
  }
  if (active) {
    const size_t idx = ((size_t)(b * Hn + h) * NS + split) * Sn + q;
    float* pp = &pacc[idx * 32];
#pragma unroll
    for (int i = 0; i < 8; ++i) {
      float4 v = make_float4(acc[i * 4], acc[i * 4 + 1], acc[i * 4 + 2], acc[i * 4 + 3]);
      *(float4*)&pp[i * 4] = v;
    }
    *(float2*)&pml[idx * 2] = make_float2(m, l);
  }
}

// ---------- merge key-splits, write scrambled P: P[b].flat[h*L*D + q*D + d] ----------
template <int NS>
__global__ __launch_bounds__(256) void combine_kernel(const float* __restrict__ pacc,
                                                      const float* __restrict__ pml,
                                                      const int* __restrict__ len,
                                                      float* __restrict__ P) {
  const int h = blockIdx.y, b = blockIdx.z;
  const int L = len[b];
  const int q = blockIdx.x * 256 + threadIdx.x;
  if (q >= L) return;
  const int chunk = ((L + NS * 64 - 1) / (NS * 64)) * 64;
  const size_t base = (size_t)(b * Hn + h) * NS * Sn;

  float M = -INFINITY;
  int ns = 0;
  float ms[NS], ls[NS];
#pragma unroll
  for (int sp = 0; sp < NS; ++sp) {
    if (sp * chunk < L) {
      float2 ml = *(const float2*)&pml[(base + (size_t)sp * Sn + q) * 2];
      ms[sp] = ml.x; ls[sp] = ml.y;
      M = fmaxf(M, ml.x);
      ns = sp + 1;
    }
  }
  float T = 0.f;
  float o[32];
#pragma unroll
  for (int d = 0; d < 32; ++d) o[d] = 0.f;
  for (int sp = 0; sp < ns; ++sp) {
    float w = __expf(ms[sp] - M);
    T += ls[sp] * w;
    const float4* pp = (const float4*)&pacc[(base + (size_t)sp * Sn + q) * 32];
#pragma unroll
    for (int i = 0; i < 8; ++i) {
      float4 v = pp[i];
      o[i * 4 + 0] = fmaf(w, v.x, o[i * 4 + 0]);
      o[i * 4 + 1] = fmaf(w, v.y, o[i * 4 + 1]);
      o[i * 4 + 2] = fmaf(w, v.z, o[i * 4 + 2]);
      o[i * 4 + 3] = fmaf(w, v.w, o[i * 4 + 3]);
    }
  }
  const float inv = 1.0f / T;
  float* dst = &P[(size_t)b * Sn * En + (size_t)h * L * Dn + (size_t)q * Dn];
#pragma unroll
  for (int i = 0; i < 8; ++i) {
    float4 v = make_float4(o[i * 4] * inv, o[i * 4 + 1] * inv,
                           o[i * 4 + 2] * inv, o[i * 4 + 3] * inv);
    *(float4*)&dst[i * 4] = v;
  }
}

// ---------- zero P tail [L*E, S*E) per batch ----------
__global__ __launch_bounds__(256) void ztail_kernel(const int* __restrict__ len,
                                                    float* __restrict__ P) {
  const int b = blockIdx.y;
  const int L = len[b];
  const int idx = (blockIdx.x * 256 + threadIdx.x) * 4;
  if (idx >= L * En)
    *(float4*)&P[(size_t)b * Sn * En + idx] = make_float4(0.f, 0.f, 0.f, 0.f);
}

extern "C" void kernel_launch(void* const* d_in, const int* in_sizes, int n_in,
                              void* d_out, int out_size, void* d_ws, size_t ws_size,
                              hipStream_t stream) {
  (void)in_sizes; (void)n_in; (void)out_size;
  const float* x  = (const float*)d_in[0];  // fp32 (B,S,E)
  const int* mask = (const int*)d_in[1];    // int32 (B,S)
  const float* Wq = (const float*)d_in[2];  // fp32 (E,E)
  const float* Wk = (const float*)d_in[3];
  const float* Wv = (const float*)d_in[4];
  const float* Wo = (const float*)d_in[5];
  float* out = (float*)d_out;               // fp32 (B,S,E)

  // workspace (fp32): lengths | Q | K | V | P | pacc | pml
  float* wsf = (float*)d_ws;
  int* lengths = (int*)d_ws;
  const size_t BHSD = (size_t)Bn * Hn * Sn * Dn;  // 2,097,152
  float* Qw = wsf + 64;
  float* Kw = Qw + BHSD;
  float* Vw = Kw + BHSD;
  float* Pw = Vw + BHSD;
  float* pacc = Pw + (size_t)Bn * Sn * En;

  // NSPLIT=8 needs ~105 MB; fall back to 4 (~71 MB, proven) if ws is small.
  const size_t fixed = 64 + 3 * BHSD + (size_t)Bn * Sn * En;
  const size_t per_split = (size_t)Bn * Hn * Sn * 34;  // acc32 + ml2 floats
  const bool use8 = ws_size >= (fixed + 8 * per_split) * sizeof(float);
  const int nsplit = use8 ? 8 : 4;
  float* pml = pacc + (size_t)Bn * Hn * nsplit * Sn * 32;

  len_kernel<<<dim3(Bn), 256, 0, stream>>>(mask, lengths);
  gemm_k<128, 128, 8, 8, 0><<<dim3(6, 64), 256, 0, stream>>>(
      x, Wq, Wk, Wv, Qw, Kw, Vw, nullptr);
  if (use8) {
    attn_kernel<8><<<dim3((Sn / 128) * 8, Hn, Bn), 128, 0, stream>>>(
        Qw, Kw, Vw, lengths, pacc, pml);
    combine_kernel<8><<<dim3(Sn / 256, Hn, Bn), 256, 0, stream>>>(
        pacc, pml, lengths, Pw);
  } else {
    attn_kernel<4><<<dim3((Sn / 128) * 4, Hn, Bn), 128, 0, stream>>>(
        Qw, Kw, Vw, lengths, pacc, pml);
    combine_kernel<4><<<dim3(Sn / 256, Hn, Bn), 256, 0, stream>>>(
        pacc, pml, lengths, Pw);
  }
  ztail_kernel<<<dim3(Sn * En / 1024, Bn), 256, 0, stream>>>(lengths, Pw);
  gemm_k<64, 128, 4, 8, 1><<<dim3(2, 128), 256, 0, stream>>>(
      Pw, Wo, Wo, Wo, nullptr, nullptr, nullptr, out);
}